// Round 4
// baseline (1414.636 us; speedup 1.0000x reference)
//
#include <hip/hip_runtime.h>
#include <math.h>

#define N_NODES 100000
#define N_EDGES 1200000
#define N_GRAPHS 16
#define CH 64
#define HEADS 4
#define GL 6
#define IN_DIM 261
#define GDIM 24
#define LIN 32
#define LL 3
#define EPSN 1e-5f
#define GEMM_GRID 782
#define NTILES 1563   // ceil(N_NODES/64)

__device__ __forceinline__ float gelu_exact(float x) {
  return 0.5f * x * (1.0f + erff(x * 0.70710678118654752440f));
}

__device__ __forceinline__ float ln32(float x, float w, float b) {
  float m = x;
  m += __shfl_xor(m, 1); m += __shfl_xor(m, 2); m += __shfl_xor(m, 4);
  m += __shfl_xor(m, 8); m += __shfl_xor(m, 16);
  m *= (1.0f / 32.0f);
  float d = x - m;
  float v = d * d;
  v += __shfl_xor(v, 1); v += __shfl_xor(v, 2); v += __shfl_xor(v, 4);
  v += __shfl_xor(v, 8); v += __shfl_xor(v, 16);
  v *= (1.0f / 32.0f);
  return d * rsqrtf(v + EPSN) * w + b;
}

// ---------------- setup: CSR build (sort edges by dst) ----------------
__global__ void k_count_deg(const int* __restrict__ dst, int* __restrict__ deg) {
  int e = blockIdx.x * 256 + threadIdx.x;
  if (e < N_EDGES) atomicAdd(&deg[dst[e]], 1);
}

__global__ void k_block_sums(const int* __restrict__ deg, int* __restrict__ bsum) {
  __shared__ int sh[256];
  int i = blockIdx.x * 256 + threadIdx.x;
  sh[threadIdx.x] = (i < N_NODES) ? deg[i] : 0;
  __syncthreads();
  for (int s = 128; s > 0; s >>= 1) {
    if (threadIdx.x < s) sh[threadIdx.x] += sh[threadIdx.x + s];
    __syncthreads();
  }
  if (threadIdx.x == 0) bsum[blockIdx.x] = sh[0];
}

__global__ void k_scan_bsums(int* __restrict__ bsum, int nb, int* __restrict__ off) {
  __shared__ int sh[512];
  int i = threadIdx.x;
  int v = (i < nb) ? bsum[i] : 0;
  sh[i] = v;
  __syncthreads();
  for (int s = 1; s < 512; s <<= 1) {
    int t = (i >= s) ? sh[i - s] : 0;
    __syncthreads();
    sh[i] += t;
    __syncthreads();
  }
  if (i < nb) bsum[i] = sh[i] - v;
  if (i == nb - 1) off[N_NODES] = sh[i];
}

__global__ void k_scan_final(const int* __restrict__ deg, const int* __restrict__ bsum,
                             int* __restrict__ off, int* __restrict__ cur) {
  __shared__ int sh[256];
  int i = blockIdx.x * 256 + threadIdx.x;
  int v = (i < N_NODES) ? deg[i] : 0;
  sh[threadIdx.x] = v;
  __syncthreads();
  for (int s = 1; s < 256; s <<= 1) {
    int t = (threadIdx.x >= s) ? sh[threadIdx.x - s] : 0;
    __syncthreads();
    sh[threadIdx.x] += t;
    __syncthreads();
  }
  if (i < N_NODES) {
    int ex = bsum[blockIdx.x] + sh[threadIdx.x] - v;
    off[i] = ex;
    cur[i] = ex;
  }
}

__global__ void k_scatter(const int* __restrict__ src, const int* __restrict__ dst,
                          int* __restrict__ cur, int* __restrict__ ssrc) {
  int e = blockIdx.x * 256 + threadIdx.x;
  if (e < N_EDGES) {
    int p = atomicAdd(&cur[dst[e]], 1);
    ssrc[p] = src[e];
  }
}

__global__ void k_graph_starts(const int* __restrict__ batch, int* __restrict__ gstart) {
  int g = threadIdx.x;
  if (g > N_GRAPHS) return;
  int lo = 0, hi = N_NODES;
  while (lo < hi) {
    int mid = (lo + hi) >> 1;
    if (batch[mid] < g) lo = mid + 1; else hi = mid;
  }
  gstart[g] = lo;
}

// ---------------- per-layer: GEMM (t = X @ W) + attention logits ----------------
// Persistent: 782 blocks x 256 threads; each block loops over 64-row tiles with
// register prefetch of the next tile/chunk (T14 async-stage: global->reg early,
// ds_write late). Single LDS buffer, 2 barriers per chunk.
__global__ __launch_bounds__(256) void k_gemm_logits(
    const float* __restrict__ Xin, int K, const float* __restrict__ W,
    const float* __restrict__ a_src, const float* __restrict__ a_dst,
    float* __restrict__ T, float* __restrict__ ES, float* __restrict__ ED) {
  __shared__ float sX[64][68];  // [row][k], pad 4
  __shared__ float sW[64][68];  // [k][col]
  const int tid = threadIdx.x;
  const int rg = tid >> 4;      // 0..15 -> rows rg*4..+3
  const int cg = tid & 15;      // 0..15 -> cols cg*4..+3
  const int stride = gridDim.x;

  // epilogue constants
  const int c0 = cg * 4;
  const int h = cg >> 2;
  float as[4], ad[4];
  #pragma unroll
  for (int j = 0; j < 4; ++j) {
    as[j] = a_src[c0 + j];
    ad[j] = a_dst[c0 + j];
  }

  if (K == 64) {
    // ---- stage W once per block (into LDS before first barrier) ----
    #pragma unroll
    for (int t = 0; t < 4; ++t) {
      int j = tid + (t << 8);
      int k = j >> 4, c4 = (j & 15) << 2;
      float4 v = *(const float4*)(W + (size_t)k * 64 + c4);
      *(float4*)&sW[k][c4] = v;
    }
    // ---- prefetch first tile's X into regs ----
    float4 xv[4];
    {
      long r0 = (long)blockIdx.x * 64;
      #pragma unroll
      for (int t = 0; t < 4; ++t) {
        int j = tid + (t << 8);
        int row = j >> 4, k4 = (j & 15) << 2;
        xv[t] = (r0 + row < N_NODES) ? *(const float4*)(Xin + (r0 + row) * 64 + k4)
                                     : make_float4(0.f, 0.f, 0.f, 0.f);
      }
    }
    for (int tile = blockIdx.x; tile < NTILES; tile += stride) {
      const long r0 = (long)tile * 64;
      // write prefetched regs to LDS
      #pragma unroll
      for (int t = 0; t < 4; ++t) {
        int j = tid + (t << 8);
        int row = j >> 4, k4 = (j & 15) << 2;
        *(float4*)&sX[row][k4] = xv[t];
      }
      __syncthreads();
      // issue next tile's loads (latency hides under compute below)
      const long nt = (long)tile + stride;
      if (nt < NTILES) {
        long nr0 = nt * 64;
        #pragma unroll
        for (int t = 0; t < 4; ++t) {
          int j = tid + (t << 8);
          int row = j >> 4, k4 = (j & 15) << 2;
          xv[t] = (nr0 + row < N_NODES) ? *(const float4*)(Xin + (nr0 + row) * 64 + k4)
                                        : make_float4(0.f, 0.f, 0.f, 0.f);
        }
      }
      // compute
      float acc[4][4];
      #pragma unroll
      for (int i = 0; i < 4; ++i)
        #pragma unroll
        for (int j = 0; j < 4; ++j) acc[i][j] = 0.f;
      #pragma unroll 4
      for (int k4 = 0; k4 < 64; k4 += 4) {
        float4 x0 = *(const float4*)&sX[rg * 4 + 0][k4];
        float4 x1 = *(const float4*)&sX[rg * 4 + 1][k4];
        float4 x2 = *(const float4*)&sX[rg * 4 + 2][k4];
        float4 x3 = *(const float4*)&sX[rg * 4 + 3][k4];
        float4 w0 = *(const float4*)&sW[k4 + 0][c0];
        float4 w1 = *(const float4*)&sW[k4 + 1][c0];
        float4 w2 = *(const float4*)&sW[k4 + 2][c0];
        float4 w3 = *(const float4*)&sW[k4 + 3][c0];
        float xr[4][4] = {{x0.x, x0.y, x0.z, x0.w},
                          {x1.x, x1.y, x1.z, x1.w},
                          {x2.x, x2.y, x2.z, x2.w},
                          {x3.x, x3.y, x3.z, x3.w}};
        float wr[4][4] = {{w0.x, w0.y, w0.z, w0.w},
                          {w1.x, w1.y, w1.z, w1.w},
                          {w2.x, w2.y, w2.z, w2.w},
                          {w3.x, w3.y, w3.z, w3.w}};
        #pragma unroll
        for (int p = 0; p < 4; ++p)
          #pragma unroll
          for (int i = 0; i < 4; ++i)
            #pragma unroll
            for (int j = 0; j < 4; ++j)
              acc[i][j] = fmaf(xr[i][p], wr[p][j], acc[i][j]);
      }
      // epilogue
      #pragma unroll
      for (int i = 0; i < 4; ++i) {
        const long row = r0 + rg * 4 + i;
        if (row >= N_NODES) continue;
        *(float4*)(T + row * 64 + c0) = make_float4(acc[i][0], acc[i][1], acc[i][2], acc[i][3]);
        float vs = 0.f, vd = 0.f;
        #pragma unroll
        for (int j = 0; j < 4; ++j) {
          vs = fmaf(acc[i][j], as[j], vs);
          vd = fmaf(acc[i][j], ad[j], vd);
        }
        vs += __shfl_xor(vs, 1); vs += __shfl_xor(vs, 2);
        vd += __shfl_xor(vd, 1); vd += __shfl_xor(vd, 2);
        if ((cg & 3) == 0) {
          ES[row * 4 + h] = vs;
          ED[row * 4 + h] = vd;
        }
      }
      __syncthreads();
    }
  } else {
    // generic K (layer 0, K=261): chunked, scalar staging, prefetch next chunk
    const int nchunks = (K + 63) >> 6;
    const int srow = tid >> 6;      // 0..3  (+4t)
    const int sk = tid & 63;
    float xs[16];
    float4 wv[4];
    // prefetch (tile=blockIdx.x, chunk=0)
    {
      long r0 = (long)blockIdx.x * 64;
      int kl = min(64, K);
      #pragma unroll
      for (int t = 0; t < 16; ++t) {
        int row = srow + 4 * t;
        xs[t] = (sk < kl && r0 + row < N_NODES) ? Xin[(r0 + row) * (long)K + sk] : 0.f;
      }
      #pragma unroll
      for (int t = 0; t < 4; ++t) {
        int j = tid + (t << 8);
        int k = j >> 4, c4 = (j & 15) << 2;
        wv[t] = (k < kl) ? *(const float4*)(W + (size_t)k * 64 + c4)
                         : make_float4(0.f, 0.f, 0.f, 0.f);
      }
    }
    for (int tile = blockIdx.x; tile < NTILES; tile += stride) {
      const long r0 = (long)tile * 64;
      float acc[4][4];
      #pragma unroll
      for (int i = 0; i < 4; ++i)
        #pragma unroll
        for (int j = 0; j < 4; ++j) acc[i][j] = 0.f;
      for (int c = 0; c < nchunks; ++c) {
        // write prefetched regs to LDS
        #pragma unroll
        for (int t = 0; t < 16; ++t) sX[srow + 4 * t][sk] = xs[t];
        #pragma unroll
        for (int t = 0; t < 4; ++t) {
          int j = tid + (t << 8);
          int k = j >> 4, c4 = (j & 15) << 2;
          *(float4*)&sW[k][c4] = wv[t];
        }
        __syncthreads();
        // prefetch next (chunk+1) or (tile+stride, chunk 0)
        int nc = c + 1;
        long ntile = tile;
        if (nc == nchunks) { nc = 0; ntile = (long)tile + stride; }
        if (ntile < NTILES) {
          long nr0 = ntile * 64;
          int nkc = nc << 6;
          int nkl = min(64, K - nkc);
          #pragma unroll
          for (int t = 0; t < 16; ++t) {
            int row = srow + 4 * t;
            xs[t] = (sk < nkl && nr0 + row < N_NODES)
                        ? Xin[(nr0 + row) * (long)K + nkc + sk] : 0.f;
          }
          #pragma unroll
          for (int t = 0; t < 4; ++t) {
            int j = tid + (t << 8);
            int k = j >> 4, c4 = (j & 15) << 2;
            wv[t] = (k < nkl) ? *(const float4*)(W + (size_t)(nkc + k) * 64 + c4)
                              : make_float4(0.f, 0.f, 0.f, 0.f);
          }
        }
        // compute (full 64 k, zero-padded)
        #pragma unroll 4
        for (int k4 = 0; k4 < 64; k4 += 4) {
          float4 x0 = *(const float4*)&sX[rg * 4 + 0][k4];
          float4 x1 = *(const float4*)&sX[rg * 4 + 1][k4];
          float4 x2 = *(const float4*)&sX[rg * 4 + 2][k4];
          float4 x3 = *(const float4*)&sX[rg * 4 + 3][k4];
          float4 w0 = *(const float4*)&sW[k4 + 0][c0];
          float4 w1 = *(const float4*)&sW[k4 + 1][c0];
          float4 w2 = *(const float4*)&sW[k4 + 2][c0];
          float4 w3 = *(const float4*)&sW[k4 + 3][c0];
          float xr[4][4] = {{x0.x, x0.y, x0.z, x0.w},
                            {x1.x, x1.y, x1.z, x1.w},
                            {x2.x, x2.y, x2.z, x2.w},
                            {x3.x, x3.y, x3.z, x3.w}};
          float wr[4][4] = {{w0.x, w0.y, w0.z, w0.w},
                            {w1.x, w1.y, w1.z, w1.w},
                            {w2.x, w2.y, w2.z, w2.w},
                            {w3.x, w3.y, w3.z, w3.w}};
          #pragma unroll
          for (int p = 0; p < 4; ++p)
            #pragma unroll
            for (int i = 0; i < 4; ++i)
              #pragma unroll
              for (int j = 0; j < 4; ++j)
                acc[i][j] = fmaf(xr[i][p], wr[p][j], acc[i][j]);
        }
        __syncthreads();
      }
      // epilogue
      #pragma unroll
      for (int i = 0; i < 4; ++i) {
        const long row = r0 + rg * 4 + i;
        if (row >= N_NODES) continue;
        *(float4*)(T + row * 64 + c0) = make_float4(acc[i][0], acc[i][1], acc[i][2], acc[i][3]);
        float vs = 0.f, vd = 0.f;
        #pragma unroll
        for (int j = 0; j < 4; ++j) {
          vs = fmaf(acc[i][j], as[j], vs);
          vd = fmaf(acc[i][j], ad[j], vd);
        }
        vs += __shfl_xor(vs, 1); vs += __shfl_xor(vs, 2);
        vd += __shfl_xor(vd, 1); vd += __shfl_xor(vd, 2);
        if ((cg & 3) == 0) {
          ES[row * 4 + h] = vs;
          ED[row * 4 + h] = vd;
        }
      }
    }
  }
}

// ---------------- per-layer: edge softmax + aggregate (wave per node) ----------------
__global__ __launch_bounds__(256) void k_edge_agg(
    const float* __restrict__ T, const float* __restrict__ ES, const float* __restrict__ ED,
    const int* __restrict__ off, const int* __restrict__ ssrc,
    const float* __restrict__ bias, float* __restrict__ F) {
  const int lane = threadIdx.x & 63;
  const int n = blockIdx.x * 4 + (threadIdx.x >> 6);
  if (n >= N_NODES) return;
  const int e0 = off[n];
  const int ec = off[n + 1] - e0;
  const int hd = lane & 3;
  const int qh = lane >> 4;
  const float ed_h = ED[n * 4 + hd];
  float x0 = ES[n * 4 + hd] + ed_h;
  x0 = fmaxf(x0, 0.2f * x0);
  float m_run = x0;
  float s_run = 1.0f;
  const float* Tl = T + lane;
  float acc = Tl[(long)n * 64];
  for (int base = 0; base < ec; base += 16) {
    const int eidx = base + (lane >> 2);
    const bool valid = eidx < ec;
    const int sv = valid ? ssrc[e0 + eidx] : n;
    float v = ES[sv * 4 + hd] + ed_h;
    float logit = valid ? fmaxf(v, 0.2f * v) : -1e30f;
    float cm = logit;
    cm = fmaxf(cm, __shfl_xor(cm, 4));
    cm = fmaxf(cm, __shfl_xor(cm, 8));
    cm = fmaxf(cm, __shfl_xor(cm, 16));
    cm = fmaxf(cm, __shfl_xor(cm, 32));
    const float new_m = fmaxf(m_run, cm);
    const float scale = __expf(m_run - new_m);
    const float p = valid ? __expf(logit - new_m) : 0.f;
    float ps = p;
    ps += __shfl_xor(ps, 4); ps += __shfl_xor(ps, 8);
    ps += __shfl_xor(ps, 16); ps += __shfl_xor(ps, 32);
    s_run = fmaf(s_run, scale, ps);
    m_run = new_m;
    acc *= __shfl(scale, qh);
    int rows[16];
    float al[16], tv[16];
    #pragma unroll
    for (int e = 0; e < 16; ++e) rows[e] = __shfl(sv, e << 2);
    #pragma unroll
    for (int e = 0; e < 16; ++e) al[e] = __shfl(p, (e << 2) | qh);
    #pragma unroll
    for (int e = 0; e < 16; ++e) tv[e] = Tl[(long)rows[e] * 64];
    #pragma unroll
    for (int e = 0; e < 16; ++e) acc = fmaf(al[e], tv[e], acc);
  }
  const float s_q = __shfl(s_run, qh);
  const float o = acc / (s_q + 1e-16f) + bias[lane];
  F[(long)n * 64 + lane] = gelu_exact(o);
}

// ---------------- GraphNorm: partial moments (no atomics/memset) ----------------
__global__ void k_graph_moments(const float* __restrict__ F, const int* __restrict__ gstart,
                                float* __restrict__ SP, float* __restrict__ SQP) {
  const int g = blockIdx.x;
  const int s0 = gstart[g];
  const int rows = gstart[g + 1] - s0;
  const int lane = threadIdx.x & 63;
  const int w = threadIdx.x >> 6;
  float sum = 0.f, sq = 0.f;
  for (int r = blockIdx.y * 4 + w; r < rows; r += gridDim.y * 4) {
    float v = F[(long)(s0 + r) * 64 + lane];
    sum += v;
    sq = fmaf(v, v, sq);
  }
  __shared__ float ls[4][64];
  __shared__ float lq[4][64];
  ls[w][lane] = sum;
  lq[w][lane] = sq;
  __syncthreads();
  if (w == 0) {
    float a = ls[0][lane] + ls[1][lane] + ls[2][lane] + ls[3][lane];
    float b = lq[0][lane] + lq[1][lane] + lq[2][lane] + lq[3][lane];
    SP[(blockIdx.y * N_GRAPHS + g) * 64 + lane] = a;
    SQP[(blockIdx.y * N_GRAPHS + g) * 64 + lane] = b;
  }
}

__global__ void k_graph_stats(const float* __restrict__ SP, const float* __restrict__ SQP,
                              const int* __restrict__ gstart, const float* __restrict__ ms,
                              float* __restrict__ MM, float* __restrict__ IS) {
  const int i = threadIdx.x;
  const int g = i >> 6, c = i & 63;
  float s = 0.f, q = 0.f;
  #pragma unroll
  for (int b = 0; b < 8; ++b) {
    s += SP[(b * N_GRAPHS + g) * 64 + c];
    q += SQP[(b * N_GRAPHS + g) * 64 + c];
  }
  const float cnt = fmaxf((float)(gstart[g + 1] - gstart[g]), 1.0f);
  const float mean = s / cnt;
  const float mm = mean * ms[c];
  float var = q / cnt - 2.f * mm * mean + mm * mm;
  MM[i] = mm;
  IS[i] = rsqrtf(fmaxf(var, 0.f) + EPSN);
}

__global__ void k_norm_res(const float* __restrict__ F, const int* __restrict__ batch,
                           const float* __restrict__ MM, const float* __restrict__ IS,
                           const float* __restrict__ w, const float* __restrict__ b,
                           float* __restrict__ X, int residual) {
  const long i4 = (long)blockIdx.x * 256 + threadIdx.x;
  const int n = (int)(i4 >> 4);
  const int c4 = (int)(i4 & 15) << 2;
  const int g = batch[n];
  float4 f = *(const float4*)(F + i4 * 4);
  float4 mm = *(const float4*)(MM + g * 64 + c4);
  float4 is = *(const float4*)(IS + g * 64 + c4);
  float4 wv = *(const float4*)(w + c4);
  float4 bv = *(const float4*)(b + c4);
  float4 y;
  y.x = fmaf(wv.x * (f.x - mm.x), is.x, bv.x);
  y.y = fmaf(wv.y * (f.y - mm.y), is.y, bv.y);
  y.z = fmaf(wv.z * (f.z - mm.z), is.z, bv.z);
  y.w = fmaf(wv.w * (f.w - mm.w), is.w, bv.w);
  float4* xp = (float4*)(X + i4 * 4);
  if (residual) {
    float4 xo = *xp;
    y.x += xo.x; y.y += xo.y; y.z += xo.z; y.w += xo.w;
  }
  *xp = y;
}

// ---------------- pooled MLP head (one block) ----------------
__global__ __launch_bounds__(512) void k_mlp(
    const float* __restrict__ SP, const int* __restrict__ gstart, const float* __restrict__ gf,
    const float* __restrict__ W0, const float* __restrict__ b0,
    const float* __restrict__ lw0, const float* __restrict__ lb0,
    const float* __restrict__ Wg, const float* __restrict__ bg,
    const float* __restrict__ lwg, const float* __restrict__ lbg,
    const float* __restrict__ hW, const float* __restrict__ hb,
    float* __restrict__ out) {
  __shared__ float P[16][88];
  __shared__ float Z[16][32];
  const int tid = threadIdx.x;
  for (int i = tid; i < 16 * 88; i += 512) {
    int g = i / 88, c = i - g * 88;
    float v;
    if (c < 64) {
      float s = 0.f;
      #pragma unroll
      for (int b = 0; b < 8; ++b) s += SP[(b * N_GRAPHS + g) * 64 + c];
      float cnt = fmaxf((float)(gstart[g + 1] - gstart[g]), 1.0f);
      v = s / cnt;
    } else {
      v = gf[g * GDIM + (c - 64)];
    }
    P[g][c] = v;
  }
  __syncthreads();
  const int g = tid >> 5, c = tid & 31;
  float acc = b0[c];
  for (int k = 0; k < 88; ++k) acc = fmaf(P[g][k], W0[k * 32 + c], acc);
  float z = ln32(gelu_exact(acc), lw0[c], lb0[c]);
  for (int l = 0; l < LL; ++l) {
    Z[g][c] = z;
    __syncthreads();
    float a2 = bg[l * 32 + c];
    const float* Wl = Wg + l * 32 * 32;
    for (int k = 0; k < 32; ++k) a2 = fmaf(Z[g][k], Wl[k * 32 + c], a2);
    __syncthreads();
    z = ln32(gelu_exact(a2), lwg[l * 32 + c], lbg[l * 32 + c]) + z;
  }
  Z[g][c] = z * hW[c];
  __syncthreads();
  if (c == 0) {
    float s = 0.f;
    for (int k = 0; k < 32; ++k) s += Z[g][k];
    out[g] = s + hb[0];
  }
}

extern "C" void kernel_launch(void* const* d_in, const int* in_sizes, int n_in,
                              void* d_out, int out_size, void* d_ws, size_t ws_size,
                              hipStream_t stream) {
  const float* x   = (const float*)d_in[0];
  const int*   ei  = (const int*)d_in[1];
  const int* batch = (const int*)d_in[2];
  const float* gf  = (const float*)d_in[3];
  const float* W0  = (const float*)d_in[4];
  const float* as0 = (const float*)d_in[5];
  const float* ad0 = (const float*)d_in[6];
  const float* b0  = (const float*)d_in[7];
  const float* gw0 = (const float*)d_in[8];
  const float* gb0 = (const float*)d_in[9];
  const float* gm0 = (const float*)d_in[10];
  const float* Wg  = (const float*)d_in[11];
  const float* asg = (const float*)d_in[12];
  const float* adg = (const float*)d_in[13];
  const float* bg  = (const float*)d_in[14];
  const float* gwg = (const float*)d_in[15];
  const float* gbg = (const float*)d_in[16];
  const float* gmg = (const float*)d_in[17];
  const float* mW0 = (const float*)d_in[18];
  const float* mb0 = (const float*)d_in[19];
  const float* lw0 = (const float*)d_in[20];
  const float* lb0 = (const float*)d_in[21];
  const float* mWg = (const float*)d_in[22];
  const float* mbg = (const float*)d_in[23];
  const float* lwg = (const float*)d_in[24];
  const float* lbg = (const float*)d_in[25];
  const float* hW  = (const float*)d_in[26];
  const float* hb  = (const float*)d_in[27];
  float* out = (float*)d_out;
  const int* src = ei;
  const int* dst = ei + N_EDGES;

  char* p = (char*)d_ws;
  auto alloc = [&](size_t bytes) {
    char* r = p;
    p += (bytes + 255) & ~(size_t)255;
    return (void*)r;
  };
  float* X  = (float*)alloc((size_t)N_NODES * 64 * 4);
  float* T  = (float*)alloc((size_t)N_NODES * 64 * 4);
  float* F  = (float*)alloc((size_t)N_NODES * 64 * 4);
  float* ES = (float*)alloc((size_t)N_NODES * 4 * 4);
  float* ED = (float*)alloc((size_t)N_NODES * 4 * 4);
  int* ssrc = (int*)alloc((size_t)N_EDGES * 4);
  int* deg  = (int*)alloc((size_t)N_NODES * 4);
  int* off  = (int*)alloc((size_t)(N_NODES + 1) * 4);
  int* cur  = (int*)alloc((size_t)N_NODES * 4);
  int* bsum = (int*)alloc(4096);
  int* gstart = (int*)alloc((N_GRAPHS + 1) * 4);
  float* SP  = (float*)alloc(8 * N_GRAPHS * 64 * 4);
  float* SQP = (float*)alloc(8 * N_GRAPHS * 64 * 4);
  float* MM  = (float*)alloc(N_GRAPHS * 64 * 4);
  float* IS  = (float*)alloc(N_GRAPHS * 64 * 4);
  (void)ws_size; (void)in_sizes; (void)n_in; (void)out_size;

  const int NB = (N_NODES + 255) / 256;
  hipMemsetAsync(deg, 0, (size_t)N_NODES * 4, stream);
  k_count_deg<<<(N_EDGES + 255) / 256, 256, 0, stream>>>(dst, deg);
  k_block_sums<<<NB, 256, 0, stream>>>(deg, bsum);
  k_scan_bsums<<<1, 512, 0, stream>>>(bsum, NB, off);
  k_scan_final<<<NB, 256, 0, stream>>>(deg, bsum, off, cur);
  k_scatter<<<(N_EDGES + 255) / 256, 256, 0, stream>>>(src, dst, cur, ssrc);
  k_graph_starts<<<1, 32, 0, stream>>>(batch, gstart);

  for (int l = 0; l < 1 + GL; ++l) {
    const float* Xin = (l == 0) ? x : X;
    const int K = (l == 0) ? IN_DIM : 64;
    const float* Wl  = (l == 0) ? W0  : (Wg  + (size_t)(l - 1) * 64 * 64);
    const float* asl = (l == 0) ? as0 : (asg + (size_t)(l - 1) * 64);
    const float* adl = (l == 0) ? ad0 : (adg + (size_t)(l - 1) * 64);
    const float* bl  = (l == 0) ? b0  : (bg  + (size_t)(l - 1) * 64);
    const float* gwl = (l == 0) ? gw0 : (gwg + (size_t)(l - 1) * 64);
    const float* gbl = (l == 0) ? gb0 : (gbg + (size_t)(l - 1) * 64);
    const float* gml = (l == 0) ? gm0 : (gmg + (size_t)(l - 1) * 64);
    k_gemm_logits<<<GEMM_GRID, 256, 0, stream>>>(Xin, K, Wl, asl, adl, T, ES, ED);
    k_edge_agg<<<N_NODES / 4, 256, 0, stream>>>(T, ES, ED, off, ssrc, bl, F);
    k_graph_moments<<<dim3(N_GRAPHS, 8), 256, 0, stream>>>(F, gstart, SP, SQP);
    k_graph_stats<<<1, 1024, 0, stream>>>(SP, SQP, gstart, gml, MM, IS);
    k_norm_res<<<(N_NODES * 64) / 1024, 256, 0, stream>>>(F, batch, MM, IS, gwl, gbl, X, l > 0);
  }

  k_graph_moments<<<dim3(N_GRAPHS, 8), 256, 0, stream>>>(X, gstart, SP, SQP);
  k_mlp<<<1, 512, 0, stream>>>(SP, gstart, gf, mW0, mb0, lw0, lb0,
                               mWg, mbg, lwg, lbg, hW, hb, out);
}

// Round 5
// 1265.749 us; speedup vs baseline: 1.1176x; 1.1176x over previous
//
#include <hip/hip_runtime.h>
#include <math.h>

#define N_NODES 100000
#define N_EDGES 1200000
#define N_GRAPHS 16
#define CH 64
#define HEADS 4
#define GL 6
#define IN_DIM 261
#define GDIM 24
#define LIN 32
#define LL 3
#define EPSN 1e-5f

typedef unsigned short u16;
typedef __attribute__((ext_vector_type(8))) short bf16x8;
typedef __attribute__((ext_vector_type(4))) float f32x4;

__device__ __forceinline__ u16 f2bf(float f) {        // RNE fp32->bf16
  unsigned u = __float_as_uint(f);
  u = (u + 0x7FFFu + ((u >> 16) & 1u)) >> 16;
  return (u16)u;
}
__device__ __forceinline__ float bf2f(u16 v) {        // exact bf16->fp32
  return __uint_as_float(((unsigned)v) << 16);
}

__device__ __forceinline__ float gelu_exact(float x) {
  return 0.5f * x * (1.0f + erff(x * 0.70710678118654752440f));
}

__device__ __forceinline__ float ln32(float x, float w, float b) {
  float m = x;
  m += __shfl_xor(m, 1); m += __shfl_xor(m, 2); m += __shfl_xor(m, 4);
  m += __shfl_xor(m, 8); m += __shfl_xor(m, 16);
  m *= (1.0f / 32.0f);
  float d = x - m;
  float v = d * d;
  v += __shfl_xor(v, 1); v += __shfl_xor(v, 2); v += __shfl_xor(v, 4);
  v += __shfl_xor(v, 8); v += __shfl_xor(v, 16);
  v *= (1.0f / 32.0f);
  return d * rsqrtf(v + EPSN) * w + b;
}

// ---------------- setup: CSR build (sort edges by dst) ----------------
__global__ void k_count_deg(const int* __restrict__ dst, int* __restrict__ deg) {
  int e = blockIdx.x * 256 + threadIdx.x;
  if (e < N_EDGES) atomicAdd(&deg[dst[e]], 1);
}

__global__ void k_block_sums(const int* __restrict__ deg, int* __restrict__ bsum) {
  __shared__ int sh[256];
  int i = blockIdx.x * 256 + threadIdx.x;
  sh[threadIdx.x] = (i < N_NODES) ? deg[i] : 0;
  __syncthreads();
  for (int s = 128; s > 0; s >>= 1) {
    if (threadIdx.x < s) sh[threadIdx.x] += sh[threadIdx.x + s];
    __syncthreads();
  }
  if (threadIdx.x == 0) bsum[blockIdx.x] = sh[0];
}

__global__ void k_scan_bsums(int* __restrict__ bsum, int nb, int* __restrict__ off) {
  __shared__ int sh[512];
  int i = threadIdx.x;
  int v = (i < nb) ? bsum[i] : 0;
  sh[i] = v;
  __syncthreads();
  for (int s = 1; s < 512; s <<= 1) {
    int t = (i >= s) ? sh[i - s] : 0;
    __syncthreads();
    sh[i] += t;
    __syncthreads();
  }
  if (i < nb) bsum[i] = sh[i] - v;
  if (i == nb - 1) off[N_NODES] = sh[i];
}

__global__ void k_scan_final(const int* __restrict__ deg, const int* __restrict__ bsum,
                             int* __restrict__ off, int* __restrict__ cur) {
  __shared__ int sh[256];
  int i = blockIdx.x * 256 + threadIdx.x;
  int v = (i < N_NODES) ? deg[i] : 0;
  sh[threadIdx.x] = v;
  __syncthreads();
  for (int s = 1; s < 256; s <<= 1) {
    int t = (threadIdx.x >= s) ? sh[threadIdx.x - s] : 0;
    __syncthreads();
    sh[threadIdx.x] += t;
    __syncthreads();
  }
  if (i < N_NODES) {
    int ex = bsum[blockIdx.x] + sh[threadIdx.x] - v;
    off[i] = ex;
    cur[i] = ex;
  }
}

__global__ void k_scatter(const int* __restrict__ src, const int* __restrict__ dst,
                          int* __restrict__ cur, int* __restrict__ ssrc) {
  int e = blockIdx.x * 256 + threadIdx.x;
  if (e < N_EDGES) {
    int p = atomicAdd(&cur[dst[e]], 1);
    ssrc[p] = src[e];
  }
}

__global__ void k_graph_starts(const int* __restrict__ batch, int* __restrict__ gstart) {
  int g = threadIdx.x;
  if (g > N_GRAPHS) return;
  int lo = 0, hi = N_NODES;
  while (lo < hi) {
    int mid = (lo + hi) >> 1;
    if (batch[mid] < g) lo = mid + 1; else hi = mid;
  }
  gstart[g] = lo;
}

// ---------------- weight prep: fp32 -> bf16 B-fragment swizzle ----------------
// Fragment order: Wswz[((cb*KS + ks)*64 + lane)*8 + i] = W[ks*32 + (lane>>4)*8 + i][cb*16 + (lane&15)]
#define W0S_ELEMS (4 * 9 * 64 * 8)   // 18432 (K padded 261->288)
#define WGS_ELEMS (4 * 2 * 64 * 8)   // 4096 per layer
__global__ void k_prep_w(const float* __restrict__ W0, const float* __restrict__ Wg,
                         u16* __restrict__ W0s, u16* __restrict__ Wgs) {
  int idx = blockIdx.x * 256 + threadIdx.x;
  if (idx < W0S_ELEMS) {
    int i = idx & 7, lane = (idx >> 3) & 63, ks = (idx >> 9) % 9, cb = idx / (9 * 512);
    int k = ks * 32 + (lane >> 4) * 8 + i, c = cb * 16 + (lane & 15);
    W0s[idx] = f2bf(k < IN_DIM ? W0[k * 64 + c] : 0.f);
  } else if (idx < W0S_ELEMS + GL * WGS_ELEMS) {
    int j = idx - W0S_ELEMS;
    int l = j / WGS_ELEMS, p = j % WGS_ELEMS;
    int i = p & 7, lane = (p >> 3) & 63, ks = (p >> 9) & 1, cb = p / (2 * 512);
    int k = ks * 32 + (lane >> 4) * 8 + i, c = cb * 16 + (lane & 15);
    Wgs[j] = f2bf(Wg[(size_t)l * 4096 + k * 64 + c]);
  }
}

// ---------------- per-layer: MFMA GEMM (T = X @ W, bf16) + attention logits ----------------
// One 16-row tile per wave; no LDS, no barriers. 100000 = 6250 * 16 exactly.
// A-frag: lane l holds X[r0 + (l&15)][ks*32 + (l>>4)*8 + i], i=0..7 (one b128).
// B-frag: from pre-swizzled Wswz (one b128).
// D: col = lane&15 (within col-block cb), row = r0 + (lane>>4)*4 + reg.
template <int KS, bool F32IN>
__global__ __launch_bounds__(256) void k_gemm_mfma(
    const void* __restrict__ Xin, const u16* __restrict__ Wswz,
    const float* __restrict__ a_src, const float* __restrict__ a_dst,
    u16* __restrict__ Tb, float* __restrict__ ES, float* __restrict__ ED) {
  const int lane = threadIdx.x & 63;
  const int wid = (blockIdx.x << 2) + (threadIdx.x >> 6);
  const int NT = N_NODES / 16;  // 6250
  if (wid >= NT) return;
  const int grp = lane >> 4, n16 = lane & 15;
  float as_l[4], ad_l[4];
  #pragma unroll
  for (int cb = 0; cb < 4; ++cb) {
    as_l[cb] = a_src[cb * 16 + n16];
    ad_l[cb] = a_dst[cb * 16 + n16];
  }
  const long r0 = (long)wid * 16;

  bf16x8 afr[KS];
  if constexpr (!F32IN) {
    const u16* xrow = (const u16*)Xin + (r0 + n16) * (KS * 32) + grp * 8;
    #pragma unroll
    for (int ks = 0; ks < KS; ++ks) afr[ks] = *(const bf16x8*)(xrow + ks * 32);
  } else {
    const float* xr = (const float*)Xin + (r0 + n16) * (size_t)IN_DIM;
    #pragma unroll
    for (int ks = 0; ks < KS; ++ks) {
      bf16x8 a;
      #pragma unroll
      for (int i = 0; i < 8; ++i) {
        int k = ks * 32 + grp * 8 + i;
        float v = (k < IN_DIM) ? xr[k] : 0.f;
        a[i] = (short)f2bf(v);
      }
      afr[ks] = a;
    }
  }

  f32x4 acc[4];
  #pragma unroll
  for (int cb = 0; cb < 4; ++cb) {
    f32x4 a = {0.f, 0.f, 0.f, 0.f};
    #pragma unroll
    for (int ks = 0; ks < KS; ++ks) {
      bf16x8 b = *(const bf16x8*)(Wswz + ((size_t)(cb * KS + ks) * 64 + lane) * 8);
      a = __builtin_amdgcn_mfma_f32_16x16x32_bf16(afr[ks], b, a, 0, 0, 0);
    }
    acc[cb] = a;
  }

  // epilogue: T (bf16) + per-head logits (head == col-block)
  #pragma unroll
  for (int r = 0; r < 4; ++r) {
    const long row = r0 + grp * 4 + r;
    #pragma unroll
    for (int cb = 0; cb < 4; ++cb) {
      float v = acc[cb][r];
      Tb[row * 64 + cb * 16 + n16] = f2bf(v);
      float s = v * as_l[cb];
      float d = v * ad_l[cb];
      s += __shfl_xor(s, 1); s += __shfl_xor(s, 2); s += __shfl_xor(s, 4); s += __shfl_xor(s, 8);
      d += __shfl_xor(d, 1); d += __shfl_xor(d, 2); d += __shfl_xor(d, 4); d += __shfl_xor(d, 8);
      if (n16 == 0) {
        ES[row * 4 + cb] = s;
        ED[row * 4 + cb] = d;
      }
    }
  }
}

// ---------------- per-layer: edge softmax + aggregate (wave per node) ----------------
__global__ __launch_bounds__(256) void k_edge_agg(
    const u16* __restrict__ Tb, const float* __restrict__ ES, const float* __restrict__ ED,
    const int* __restrict__ off, const int* __restrict__ ssrc,
    const float* __restrict__ bias, float* __restrict__ F) {
  const int lane = threadIdx.x & 63;
  const int n = blockIdx.x * 4 + (threadIdx.x >> 6);
  if (n >= N_NODES) return;
  const int e0 = off[n];
  const int ec = off[n + 1] - e0;
  const int hd = lane & 3;
  const int qh = lane >> 4;
  const float ed_h = ED[n * 4 + hd];
  float x0 = ES[n * 4 + hd] + ed_h;
  x0 = fmaxf(x0, 0.2f * x0);
  float m_run = x0;
  float s_run = 1.0f;
  const u16* Tl = Tb + lane;
  float acc = bf2f(Tl[(long)n * 64]);
  for (int base = 0; base < ec; base += 16) {
    const int eidx = base + (lane >> 2);
    const bool valid = eidx < ec;
    const int sv = valid ? ssrc[e0 + eidx] : n;
    float v = ES[sv * 4 + hd] + ed_h;
    float logit = valid ? fmaxf(v, 0.2f * v) : -1e30f;
    float cm = logit;
    cm = fmaxf(cm, __shfl_xor(cm, 4));
    cm = fmaxf(cm, __shfl_xor(cm, 8));
    cm = fmaxf(cm, __shfl_xor(cm, 16));
    cm = fmaxf(cm, __shfl_xor(cm, 32));
    const float new_m = fmaxf(m_run, cm);
    const float scale = __expf(m_run - new_m);
    const float p = valid ? __expf(logit - new_m) : 0.f;
    float ps = p;
    ps += __shfl_xor(ps, 4); ps += __shfl_xor(ps, 8);
    ps += __shfl_xor(ps, 16); ps += __shfl_xor(ps, 32);
    s_run = fmaf(s_run, scale, ps);
    m_run = new_m;
    acc *= __shfl(scale, qh);
    int rows[16];
    float al[16], tv[16];
    #pragma unroll
    for (int e = 0; e < 16; ++e) rows[e] = __shfl(sv, e << 2);
    #pragma unroll
    for (int e = 0; e < 16; ++e) al[e] = __shfl(p, (e << 2) | qh);
    #pragma unroll
    for (int e = 0; e < 16; ++e) tv[e] = bf2f(Tl[(long)rows[e] * 64]);
    #pragma unroll
    for (int e = 0; e < 16; ++e) acc = fmaf(al[e], tv[e], acc);
  }
  const float s_q = __shfl(s_run, qh);
  const float o = acc / (s_q + 1e-16f) + bias[lane];
  F[(long)n * 64 + lane] = gelu_exact(o);
}

// ---------------- GraphNorm: partial moments ----------------
__global__ void k_graph_moments(const float* __restrict__ F, const int* __restrict__ gstart,
                                float* __restrict__ SP, float* __restrict__ SQP) {
  const int g = blockIdx.x;
  const int s0 = gstart[g];
  const int rows = gstart[g + 1] - s0;
  const int lane = threadIdx.x & 63;
  const int w = threadIdx.x >> 6;
  float sum = 0.f, sq = 0.f;
  for (int r = blockIdx.y * 4 + w; r < rows; r += gridDim.y * 4) {
    float v = F[(long)(s0 + r) * 64 + lane];
    sum += v;
    sq = fmaf(v, v, sq);
  }
  __shared__ float ls[4][64];
  __shared__ float lq[4][64];
  ls[w][lane] = sum;
  lq[w][lane] = sq;
  __syncthreads();
  if (w == 0) {
    float a = ls[0][lane] + ls[1][lane] + ls[2][lane] + ls[3][lane];
    float b = lq[0][lane] + lq[1][lane] + lq[2][lane] + lq[3][lane];
    SP[(blockIdx.y * N_GRAPHS + g) * 64 + lane] = a;
    SQP[(blockIdx.y * N_GRAPHS + g) * 64 + lane] = b;
  }
}

__global__ void k_graph_stats(const float* __restrict__ SP, const float* __restrict__ SQP,
                              const int* __restrict__ gstart, const float* __restrict__ ms,
                              float* __restrict__ MM, float* __restrict__ IS) {
  const int i = threadIdx.x;
  const int g = i >> 6, c = i & 63;
  float s = 0.f, q = 0.f;
  #pragma unroll
  for (int b = 0; b < 8; ++b) {
    s += SP[(b * N_GRAPHS + g) * 64 + c];
    q += SQP[(b * N_GRAPHS + g) * 64 + c];
  }
  const float cnt = fmaxf((float)(gstart[g + 1] - gstart[g]), 1.0f);
  const float mean = s / cnt;
  const float mm = mean * ms[c];
  float var = q / cnt - 2.f * mm * mean + mm * mm;
  MM[i] = mm;
  IS[i] = rsqrtf(fmaxf(var, 0.f) + EPSN);
}

__global__ void k_norm_res(const float* __restrict__ F, const int* __restrict__ batch,
                           const float* __restrict__ MM, const float* __restrict__ IS,
                           const float* __restrict__ w, const float* __restrict__ b,
                           float* __restrict__ X, u16* __restrict__ Xb, int residual) {
  const long i4 = (long)blockIdx.x * 256 + threadIdx.x;
  const int n = (int)(i4 >> 4);
  const int c4 = (int)(i4 & 15) << 2;
  const int g = batch[n];
  float4 f = *(const float4*)(F + i4 * 4);
  float4 mm = *(const float4*)(MM + g * 64 + c4);
  float4 is = *(const float4*)(IS + g * 64 + c4);
  float4 wv = *(const float4*)(w + c4);
  float4 bv = *(const float4*)(b + c4);
  float4 y;
  y.x = fmaf(wv.x * (f.x - mm.x), is.x, bv.x);
  y.y = fmaf(wv.y * (f.y - mm.y), is.y, bv.y);
  y.z = fmaf(wv.z * (f.z - mm.z), is.z, bv.z);
  y.w = fmaf(wv.w * (f.w - mm.w), is.w, bv.w);
  float4* xp = (float4*)(X + i4 * 4);
  if (residual) {
    float4 xo = *xp;
    y.x += xo.x; y.y += xo.y; y.z += xo.z; y.w += xo.w;
  }
  *xp = y;
  union { u16 s[4]; unsigned long long ll; } pk;
  pk.s[0] = f2bf(y.x); pk.s[1] = f2bf(y.y); pk.s[2] = f2bf(y.z); pk.s[3] = f2bf(y.w);
  *(unsigned long long*)(Xb + i4 * 4) = pk.ll;
}

// ---------------- pooled MLP head (one block) ----------------
__global__ __launch_bounds__(512) void k_mlp(
    const float* __restrict__ SP, const int* __restrict__ gstart, const float* __restrict__ gf,
    const float* __restrict__ W0, const float* __restrict__ b0,
    const float* __restrict__ lw0, const float* __restrict__ lb0,
    const float* __restrict__ Wg, const float* __restrict__ bg,
    const float* __restrict__ lwg, const float* __restrict__ lbg,
    const float* __restrict__ hW, const float* __restrict__ hb,
    float* __restrict__ out) {
  __shared__ float P[16][88];
  __shared__ float Z[16][32];
  const int tid = threadIdx.x;
  for (int i = tid; i < 16 * 88; i += 512) {
    int g = i / 88, c = i - g * 88;
    float v;
    if (c < 64) {
      float s = 0.f;
      #pragma unroll
      for (int b = 0; b < 8; ++b) s += SP[(b * N_GRAPHS + g) * 64 + c];
      float cnt = fmaxf((float)(gstart[g + 1] - gstart[g]), 1.0f);
      v = s / cnt;
    } else {
      v = gf[g * GDIM + (c - 64)];
    }
    P[g][c] = v;
  }
  __syncthreads();
  const int g = tid >> 5, c = tid & 31;
  float acc = b0[c];
  for (int k = 0; k < 88; ++k) acc = fmaf(P[g][k], W0[k * 32 + c], acc);
  float z = ln32(gelu_exact(acc), lw0[c], lb0[c]);
  for (int l = 0; l < LL; ++l) {
    Z[g][c] = z;
    __syncthreads();
    float a2 = bg[l * 32 + c];
    const float* Wl = Wg + l * 32 * 32;
    for (int k = 0; k < 32; ++k) a2 = fmaf(Z[g][k], Wl[k * 32 + c], a2);
    __syncthreads();
    z = ln32(gelu_exact(a2), lwg[l * 32 + c], lbg[l * 32 + c]) + z;
  }
  Z[g][c] = z * hW[c];
  __syncthreads();
  if (c == 0) {
    float s = 0.f;
    for (int k = 0; k < 32; ++k) s += Z[g][k];
    out[g] = s + hb[0];
  }
}

extern "C" void kernel_launch(void* const* d_in, const int* in_sizes, int n_in,
                              void* d_out, int out_size, void* d_ws, size_t ws_size,
                              hipStream_t stream) {
  const float* x   = (const float*)d_in[0];
  const int*   ei  = (const int*)d_in[1];
  const int* batch = (const int*)d_in[2];
  const float* gf  = (const float*)d_in[3];
  const float* W0  = (const float*)d_in[4];
  const float* as0 = (const float*)d_in[5];
  const float* ad0 = (const float*)d_in[6];
  const float* b0  = (const float*)d_in[7];
  const float* gw0 = (const float*)d_in[8];
  const float* gb0 = (const float*)d_in[9];
  const float* gm0 = (const float*)d_in[10];
  const float* Wg  = (const float*)d_in[11];
  const float* asg = (const float*)d_in[12];
  const float* adg = (const float*)d_in[13];
  const float* bg  = (const float*)d_in[14];
  const float* gwg = (const float*)d_in[15];
  const float* gbg = (const float*)d_in[16];
  const float* gmg = (const float*)d_in[17];
  const float* mW0 = (const float*)d_in[18];
  const float* mb0 = (const float*)d_in[19];
  const float* lw0 = (const float*)d_in[20];
  const float* lb0 = (const float*)d_in[21];
  const float* mWg = (const float*)d_in[22];
  const float* mbg = (const float*)d_in[23];
  const float* lwg = (const float*)d_in[24];
  const float* lbg = (const float*)d_in[25];
  const float* hW  = (const float*)d_in[26];
  const float* hb  = (const float*)d_in[27];
  float* out = (float*)d_out;
  const int* src = ei;
  const int* dst = ei + N_EDGES;

  char* p = (char*)d_ws;
  auto alloc = [&](size_t bytes) {
    char* r = p;
    p += (bytes + 255) & ~(size_t)255;
    return (void*)r;
  };
  float* X   = (float*)alloc((size_t)N_NODES * 64 * 4);
  float* F   = (float*)alloc((size_t)N_NODES * 64 * 4);
  u16*   Xb  = (u16*)alloc((size_t)N_NODES * 64 * 2);
  u16*   Tb  = (u16*)alloc((size_t)N_NODES * 64 * 2);
  float* ES  = (float*)alloc((size_t)N_NODES * 4 * 4);
  float* ED  = (float*)alloc((size_t)N_NODES * 4 * 4);
  int* ssrc  = (int*)alloc((size_t)N_EDGES * 4);
  int* deg   = (int*)alloc((size_t)N_NODES * 4);
  int* off   = (int*)alloc((size_t)(N_NODES + 1) * 4);
  int* cur   = (int*)alloc((size_t)N_NODES * 4);
  int* bsum  = (int*)alloc(4096);
  int* gstart = (int*)alloc((N_GRAPHS + 1) * 4);
  u16* W0s   = (u16*)alloc((size_t)W0S_ELEMS * 2);
  u16* Wgs   = (u16*)alloc((size_t)GL * WGS_ELEMS * 2);
  float* SP  = (float*)alloc(8 * N_GRAPHS * 64 * 4);
  float* SQP = (float*)alloc(8 * N_GRAPHS * 64 * 4);
  float* MM  = (float*)alloc(N_GRAPHS * 64 * 4);
  float* IS  = (float*)alloc(N_GRAPHS * 64 * 4);
  (void)ws_size; (void)in_sizes; (void)n_in; (void)out_size;

  const int NB = (N_NODES + 255) / 256;
  hipMemsetAsync(deg, 0, (size_t)N_NODES * 4, stream);
  k_count_deg<<<(N_EDGES + 255) / 256, 256, 0, stream>>>(dst, deg);
  k_block_sums<<<NB, 256, 0, stream>>>(deg, bsum);
  k_scan_bsums<<<1, 512, 0, stream>>>(bsum, NB, off);
  k_scan_final<<<NB, 256, 0, stream>>>(deg, bsum, off, cur);
  k_scatter<<<(N_EDGES + 255) / 256, 256, 0, stream>>>(src, dst, cur, ssrc);
  k_graph_starts<<<1, 32, 0, stream>>>(batch, gstart);
  k_prep_w<<<(W0S_ELEMS + GL * WGS_ELEMS + 255) / 256, 256, 0, stream>>>(W0, Wg, W0s, Wgs);

  const int GG = (N_NODES / 16 + 3) / 4;  // 1563 blocks, 1 tile per wave
  for (int l = 0; l < 1 + GL; ++l) {
    const float* asl = (l == 0) ? as0 : (asg + (size_t)(l - 1) * 64);
    const float* adl = (l == 0) ? ad0 : (adg + (size_t)(l - 1) * 64);
    const float* bl  = (l == 0) ? b0  : (bg  + (size_t)(l - 1) * 64);
    const float* gwl = (l == 0) ? gw0 : (gwg + (size_t)(l - 1) * 64);
    const float* gbl = (l == 0) ? gb0 : (gbg + (size_t)(l - 1) * 64);
    const float* gml = (l == 0) ? gm0 : (gmg + (size_t)(l - 1) * 64);
    if (l == 0)
      k_gemm_mfma<9, true><<<GG, 256, 0, stream>>>(x, W0s, asl, adl, Tb, ES, ED);
    else
      k_gemm_mfma<2, false><<<GG, 256, 0, stream>>>(Xb, Wgs + (size_t)(l - 1) * WGS_ELEMS,
                                                    asl, adl, Tb, ES, ED);
    k_edge_agg<<<N_NODES / 4, 256, 0, stream>>>(Tb, ES, ED, off, ssrc, bl, F);
    k_graph_moments<<<dim3(N_GRAPHS, 8), 256, 0, stream>>>(F, gstart, SP, SQP);
    k_graph_stats<<<1, 1024, 0, stream>>>(SP, SQP, gstart, gml, MM, IS);
    k_norm_res<<<(N_NODES * 64) / 1024, 256, 0, stream>>>(F, batch, MM, IS, gwl, gbl, X, Xb, l > 0);
  }

  k_graph_moments<<<dim3(N_GRAPHS, 8), 256, 0, stream>>>(X, gstart, SP, SQP);
  k_mlp<<<1, 512, 0, stream>>>(SP, gstart, gf, mW0, mb0, lw0, lb0,
                               mWg, mbg, lwg, lbg, hW, hb, out);
}